// Round 2
// baseline (1283.306 us; speedup 1.0000x reference)
//
#include <hip/hip_runtime.h>

// GCN 2-layer, fp32 end-to-end (reference dtypes: float32 + int32 edges).
// out = tanh((Â x) W1 + b1) W2 + b2, using Â(xW1) = (Âx)W1.
// ws: deg(int,N) | dinv(f32,N) | agg(f32,N*128) | tb(f32,N*128) ≈ 52 MB

#define DFEAT 128

__global__ void k_deg_init(int* __restrict__ deg, int n) {
    int i = blockIdx.x * blockDim.x + threadIdx.x;
    if (i < n) deg[i] = 1;  // self-loop
}

__global__ void k_deg_count(const int* __restrict__ dst, int* __restrict__ deg, int e) {
    int i = blockIdx.x * blockDim.x + threadIdx.x;
    if (i < e) atomicAdd(&deg[dst[i]], 1);
}

__global__ void k_dinv(const int* __restrict__ deg, float* __restrict__ dinv, int n) {
    int i = blockIdx.x * blockDim.x + threadIdx.x;
    if (i < n) dinv[i] = rsqrtf((float)deg[i]);
}

// agg[i,:] = dinv[i]^2 * x[i,:]  (self-loop term; also zero-inits agg)
__global__ void k_selfloop(const float* __restrict__ x,
                           const float* __restrict__ dinv,
                           float* __restrict__ agg, long long total) {
    long long i = (long long)blockIdx.x * blockDim.x + threadIdx.x;
    if (i < total) {
        int node = (int)(i >> 7);
        float di = dinv[node];
        agg[i] = di * di * x[i];
    }
}

// One edge per 32-thread group; each lane handles 4 dims via float4 (16B).
__global__ void k_edge_agg(const float* __restrict__ x,
                           const int* __restrict__ src,
                           const int* __restrict__ dst,
                           const float* __restrict__ dinv,
                           float* __restrict__ agg, int e) {
    int gid = blockIdx.x * blockDim.x + threadIdx.x;
    int ei = gid >> 5;
    if (ei >= e) return;
    int lane = gid & 31;
    int s = src[ei];
    int t = dst[ei];
    float nrm = dinv[s] * dinv[t];
    const float4 v = *(const float4*)(x + (size_t)s * DFEAT + lane * 4);
    float* ao = agg + (size_t)t * DFEAT + lane * 4;
    unsafeAtomicAdd(ao + 0, nrm * v.x);
    unsafeAtomicAdd(ao + 1, nrm * v.y);
    unsafeAtomicAdd(ao + 2, nrm * v.z);
    unsafeAtomicAdd(ao + 3, nrm * v.w);
}

// [m x 128] @ [128 x 128] + bias (+tanh). 32 rows/block, 4x4 micro-tile/thread.
// LDS: W fp32 (64KB) + 32 rows fp32 (16KB) = 80KB -> 2 blocks/CU.
template <bool DO_TANH>
__global__ __launch_bounds__(256) void k_gemm(
    const float* __restrict__ in, const float* __restrict__ W,
    const float* __restrict__ bias, float* __restrict__ out, int m) {
    __shared__ float Ws[DFEAT * DFEAT];  // 64 KB
    __shared__ float xs[32][DFEAT];      // 16 KB
    const int t = threadIdx.x;
    for (int i = t * 4; i < DFEAT * DFEAT; i += 256 * 4)
        *(float4*)&Ws[i] = *(const float4*)&W[i];
    const int row0 = blockIdx.x * 32;
    for (int i = t * 4; i < 32 * DFEAT; i += 256 * 4) {
        int r = i >> 7, c = i & 127;
        int gr = row0 + r;
        float4 v = make_float4(0.f, 0.f, 0.f, 0.f);
        if (gr < m) v = *(const float4*)&in[(size_t)gr * DFEAT + c];
        *(float4*)&xs[r][c] = v;
    }
    __syncthreads();
    const int cg = t & 31;  // cols 4*cg .. 4*cg+3
    const int rg = t >> 5;  // rows rg, rg+8, rg+16, rg+24
    float acc[4][4] = {{0.f}};
    for (int k = 0; k < DFEAT; ++k) {
        float4 w = *(const float4*)&Ws[k * DFEAT + cg * 4];
        float x0 = xs[rg][k], x1 = xs[rg + 8][k], x2 = xs[rg + 16][k], x3 = xs[rg + 24][k];
        acc[0][0] += x0 * w.x; acc[0][1] += x0 * w.y; acc[0][2] += x0 * w.z; acc[0][3] += x0 * w.w;
        acc[1][0] += x1 * w.x; acc[1][1] += x1 * w.y; acc[1][2] += x1 * w.z; acc[1][3] += x1 * w.w;
        acc[2][0] += x2 * w.x; acc[2][1] += x2 * w.y; acc[2][2] += x2 * w.z; acc[2][3] += x2 * w.w;
        acc[3][0] += x3 * w.x; acc[3][1] += x3 * w.y; acc[3][2] += x3 * w.z; acc[3][3] += x3 * w.w;
    }
    float4 b = *(const float4*)&bias[cg * 4];
    for (int r = 0; r < 4; ++r) {
        int gr = row0 + rg + r * 8;
        if (gr < m) {
            float4 o;
            o.x = acc[r][0] + b.x; o.y = acc[r][1] + b.y;
            o.z = acc[r][2] + b.z; o.w = acc[r][3] + b.w;
            if (DO_TANH) { o.x = tanhf(o.x); o.y = tanhf(o.y); o.z = tanhf(o.z); o.w = tanhf(o.w); }
            *(float4*)&out[(size_t)gr * DFEAT + cg * 4] = o;
        }
    }
}

static inline size_t align256(size_t v) { return (v + 255) & ~(size_t)255; }

extern "C" void kernel_launch(void* const* d_in, const int* in_sizes, int n_in,
                              void* d_out, int out_size, void* d_ws, size_t ws_size,
                              hipStream_t stream) {
    const float* x  = (const float*)d_in[0];
    const int*   ei = (const int*)d_in[1];
    const float* W1 = (const float*)d_in[2];
    const float* b1 = (const float*)d_in[3];
    const float* W2 = (const float*)d_in[4];
    const float* b2 = (const float*)d_in[5];
    float* out = (float*)d_out;

    const int N = in_sizes[0] / DFEAT;   // 50000
    const int E = in_sizes[1] / 2;       // 640000
    const int* src = ei;
    const int* dst = ei + E;

    char* ws = (char*)d_ws;
    size_t off = 0;
    int* deg = (int*)(ws + off);       off += align256((size_t)N * 4);
    float* dinv = (float*)(ws + off);  off += align256((size_t)N * 4);
    float* agg = (float*)(ws + off);   off += align256((size_t)N * DFEAT * 4);
    float* tb = (float*)(ws + off);    // fp32 tanh buffer, N*DFEAT*4

    const long long totalF = (long long)N * DFEAT;

    k_deg_init<<<(N + 255) / 256, 256, 0, stream>>>(deg, N);
    k_deg_count<<<(E + 255) / 256, 256, 0, stream>>>(dst, deg, E);
    k_dinv<<<(N + 255) / 256, 256, 0, stream>>>(deg, dinv, N);
    k_selfloop<<<(int)((totalF + 255) / 256), 256, 0, stream>>>(x, dinv, agg, totalF);
    k_edge_agg<<<(int)(((long long)E * 32 + 255) / 256), 256, 0, stream>>>(x, src, dst, dinv, agg, E);
    k_gemm<true><<<(N + 31) / 32, 256, 0, stream>>>(agg, W1, b1, tb, N);
    k_gemm<false><<<(N + 31) / 32, 256, 0, stream>>>(tb, W2, b2, out, N);
}

// Round 3
// 294.798 us; speedup vs baseline: 4.3532x; 4.3532x over previous
//
#include <hip/hip_runtime.h>

// GCN 2-layer, fp32. out = tanh((Â x) W1 + b1) W2 + b2, with Â(xW1)=(Âx)W1.
// Round 3: CSR-by-dst pull aggregation (no fp32 atomics; round-2 push-atomic
// version was atomic-write-through bound: WRITE_SIZE 1.28 GB for 25.6 MB out).
// ws: cnt | dinv | rowptr | cursor | bsum | col | agg  ≈ 29 MB.
// GEMM1 writes tanh buffer into d_out; GEMM2 runs in-place on d_out.

#define DFEAT 128

__global__ void k_cnt_init(int* __restrict__ cnt, int n) {
    int i = blockIdx.x * blockDim.x + threadIdx.x;
    if (i < n) cnt[i] = 0;
}

__global__ void k_cnt_count(const int* __restrict__ dst, int* __restrict__ cnt, int e) {
    int i = blockIdx.x * blockDim.x + threadIdx.x;
    if (i < e) atomicAdd(&cnt[dst[i]], 1);
}

__global__ void k_dinv(const int* __restrict__ cnt, float* __restrict__ dinv, int n) {
    int i = blockIdx.x * blockDim.x + threadIdx.x;
    if (i < n) dinv[i] = rsqrtf((float)(cnt[i] + 1));  // +1 self-loop
}

// Exclusive scan of cnt -> rowptr, per-256 block; block totals -> bsum.
__global__ void k_scan1(const int* __restrict__ cnt, int* __restrict__ rowptr,
                        int* __restrict__ bsum, int n) {
    __shared__ int s[256];
    int t = threadIdx.x, g = blockIdx.x * 256 + t;
    int v = (g < n) ? cnt[g] : 0;
    s[t] = v; __syncthreads();
    for (int off = 1; off < 256; off <<= 1) {
        int a = (t >= off) ? s[t - off] : 0;
        __syncthreads();
        s[t] += a;
        __syncthreads();
    }
    if (g < n) rowptr[g] = s[t] - v;  // exclusive
    if (t == 255) bsum[blockIdx.x] = s[t];
}

// Exclusive scan of bsum (nb <= 256), single block.
__global__ void k_scan2(int* __restrict__ bsum, int nb) {
    __shared__ int s[256];
    int t = threadIdx.x;
    int v = (t < nb) ? bsum[t] : 0;
    s[t] = v; __syncthreads();
    for (int off = 1; off < 256; off <<= 1) {
        int a = (t >= off) ? s[t - off] : 0;
        __syncthreads();
        s[t] += a;
        __syncthreads();
    }
    if (t < nb) bsum[t] = s[t] - v;
}

__global__ void k_scan3(int* __restrict__ rowptr, const int* __restrict__ bsum,
                        int* __restrict__ cursor, int n, int e) {
    int g = blockIdx.x * blockDim.x + threadIdx.x;
    if (g < n) {
        int r = rowptr[g] + bsum[g >> 8];
        rowptr[g] = r;
        cursor[g] = r;
    }
    if (g == 0) rowptr[n] = e;
}

__global__ void k_scatter(const int* __restrict__ src, const int* __restrict__ dst,
                          int* __restrict__ cursor, int* __restrict__ col, int e) {
    int i = blockIdx.x * blockDim.x + threadIdx.x;
    if (i < e) {
        int p = atomicAdd(&cursor[dst[i]], 1);
        col[p] = src[i];
    }
}

// Pull aggregation: 32 lanes per node, float4 per lane (128 dims).
__global__ __launch_bounds__(256) void k_agg_pull(
    const float* __restrict__ x, const int* __restrict__ rowptr,
    const int* __restrict__ col, const float* __restrict__ dinv,
    float* __restrict__ agg, int n) {
    int gid = blockIdx.x * blockDim.x + threadIdx.x;
    int node = gid >> 5;
    if (node >= n) return;
    int lane = gid & 31;
    const float4* x4 = (const float4*)x;
    float di = dinv[node];
    float4 xv = x4[(size_t)node * 32 + lane];
    float w = di * di;
    float4 acc = make_float4(w * xv.x, w * xv.y, w * xv.z, w * xv.w);
    int c0 = rowptr[node], c1 = rowptr[node + 1];
    for (int e = c0; e < c1; ++e) {
        int s = col[e];
        float nrm = di * dinv[s];
        float4 v = x4[(size_t)s * 32 + lane];
        acc.x += nrm * v.x; acc.y += nrm * v.y;
        acc.z += nrm * v.z; acc.w += nrm * v.w;
    }
    ((float4*)agg)[(size_t)node * 32 + lane] = acc;
}

// [m x 128] @ [128 x 128] + bias (+tanh). 32 rows/block, 4x4 micro-tile/thread.
// NOTE: in/out may alias (in-place per-row-block is safe: rows staged into LDS
// behind __syncthreads before any write) — so no __restrict__ on in/out.
template <bool DO_TANH>
__global__ __launch_bounds__(256) void k_gemm(
    const float* in, const float* __restrict__ W,
    const float* __restrict__ bias, float* out, int m) {
    __shared__ float Ws[DFEAT * DFEAT];  // 64 KB
    __shared__ float xs[32][DFEAT];      // 16 KB
    const int t = threadIdx.x;
    for (int i = t * 4; i < DFEAT * DFEAT; i += 256 * 4)
        *(float4*)&Ws[i] = *(const float4*)&W[i];
    const int row0 = blockIdx.x * 32;
    for (int i = t * 4; i < 32 * DFEAT; i += 256 * 4) {
        int r = i >> 7, c = i & 127;
        int gr = row0 + r;
        float4 v = make_float4(0.f, 0.f, 0.f, 0.f);
        if (gr < m) v = *(const float4*)&in[(size_t)gr * DFEAT + c];
        *(float4*)&xs[r][c] = v;
    }
    __syncthreads();
    const int cg = t & 31;
    const int rg = t >> 5;
    float acc[4][4] = {{0.f}};
    for (int k = 0; k < DFEAT; ++k) {
        float4 w = *(const float4*)&Ws[k * DFEAT + cg * 4];
        float x0 = xs[rg][k], x1 = xs[rg + 8][k], x2 = xs[rg + 16][k], x3 = xs[rg + 24][k];
        acc[0][0] += x0 * w.x; acc[0][1] += x0 * w.y; acc[0][2] += x0 * w.z; acc[0][3] += x0 * w.w;
        acc[1][0] += x1 * w.x; acc[1][1] += x1 * w.y; acc[1][2] += x1 * w.z; acc[1][3] += x1 * w.w;
        acc[2][0] += x2 * w.x; acc[2][1] += x2 * w.y; acc[2][2] += x2 * w.z; acc[2][3] += x2 * w.w;
        acc[3][0] += x3 * w.x; acc[3][1] += x3 * w.y; acc[3][2] += x3 * w.z; acc[3][3] += x3 * w.w;
    }
    float4 b = *(const float4*)&bias[cg * 4];
    for (int r = 0; r < 4; ++r) {
        int gr = row0 + rg + r * 8;
        if (gr < m) {
            float4 o;
            o.x = acc[r][0] + b.x; o.y = acc[r][1] + b.y;
            o.z = acc[r][2] + b.z; o.w = acc[r][3] + b.w;
            if (DO_TANH) { o.x = tanhf(o.x); o.y = tanhf(o.y); o.z = tanhf(o.z); o.w = tanhf(o.w); }
            *(float4*)&out[(size_t)gr * DFEAT + cg * 4] = o;
        }
    }
}

static inline size_t align256(size_t v) { return (v + 255) & ~(size_t)255; }

extern "C" void kernel_launch(void* const* d_in, const int* in_sizes, int n_in,
                              void* d_out, int out_size, void* d_ws, size_t ws_size,
                              hipStream_t stream) {
    const float* x  = (const float*)d_in[0];
    const int*   ei = (const int*)d_in[1];
    const float* W1 = (const float*)d_in[2];
    const float* b1 = (const float*)d_in[3];
    const float* W2 = (const float*)d_in[4];
    const float* b2 = (const float*)d_in[5];
    float* out = (float*)d_out;

    const int N = in_sizes[0] / DFEAT;   // 50000
    const int E = in_sizes[1] / 2;       // 640000
    const int* src = ei;
    const int* dst = ei + E;

    char* ws = (char*)d_ws;
    size_t off = 0;
    int* cnt    = (int*)(ws + off);   off += align256((size_t)N * 4);
    float* dinv = (float*)(ws + off); off += align256((size_t)N * 4);
    int* rowptr = (int*)(ws + off);   off += align256((size_t)(N + 1) * 4);
    int* cursor = (int*)(ws + off);   off += align256((size_t)N * 4);
    int* bsum   = (int*)(ws + off);   off += align256(256 * 4);
    int* col    = (int*)(ws + off);   off += align256((size_t)E * 4);
    float* agg  = (float*)(ws + off); // N*DFEAT*4

    const int nb = (N + 255) / 256;  // 196 <= 256, required by k_scan2

    k_cnt_init<<<nb, 256, 0, stream>>>(cnt, N);
    k_cnt_count<<<(E + 255) / 256, 256, 0, stream>>>(dst, cnt, E);
    k_dinv<<<nb, 256, 0, stream>>>(cnt, dinv, N);
    k_scan1<<<nb, 256, 0, stream>>>(cnt, rowptr, bsum, N);
    k_scan2<<<1, 256, 0, stream>>>(bsum, nb);
    k_scan3<<<nb, 256, 0, stream>>>(rowptr, bsum, cursor, N, E);
    k_scatter<<<(E + 255) / 256, 256, 0, stream>>>(src, dst, cursor, col, E);
    k_agg_pull<<<((N * 32) + 255) / 256, 256, 0, stream>>>(x, rowptr, col, dinv, agg, N);
    k_gemm<true><<<(N + 31) / 32, 256, 0, stream>>>(agg, W1, b1, out, N);   // tanh -> out
    k_gemm<false><<<(N + 31) / 32, 256, 0, stream>>>(out, W2, b2, out, N);  // in-place
}

// Round 4
// 227.134 us; speedup vs baseline: 5.6500x; 1.2979x over previous
//
#include <hip/hip_runtime.h>

// GCN 2-layer. out = tanh((Â x) W1 + b1) W2 + b2, with Â(xW1)=(Âx)W1.
// Round 4: bf16 everywhere the error budget allows (threshold 2.89e-2):
//  - xb = bf16(x * dinv) folds src-norm into the features (pure-sum gather)
//  - aggregation gathers 256B bf16 rows (half the round-3 L2-miss traffic)
//  - both GEMMs fused into one MFMA kernel (16x16x32 bf16), h via LDS.
// ws: cnt | dinv | rowptr | cursor | bsum | col | xb | aggb | w1f | w2f ≈ 29 MB

#define DFEAT 128

typedef __attribute__((ext_vector_type(8))) short short8;
typedef __attribute__((ext_vector_type(4))) float float4v;

__device__ __forceinline__ float bf2f(unsigned int u16) {
    union { unsigned int i; float f; } v; v.i = u16 << 16; return v.f;
}
__device__ __forceinline__ unsigned short f2bf(float f) {
    union { unsigned int i; float f; } v; v.f = f;
    unsigned int r = v.i + 0x7fffu + ((v.i >> 16) & 1u);  // RNE
    return (unsigned short)(r >> 16);
}

__global__ void k_cnt_init(int* __restrict__ cnt, int n) {
    int i = blockIdx.x * blockDim.x + threadIdx.x;
    if (i < n) cnt[i] = 0;
}

__global__ void k_cnt_count(const int* __restrict__ dst, int* __restrict__ cnt, int e) {
    int i = blockIdx.x * blockDim.x + threadIdx.x;
    if (i < e) atomicAdd(&cnt[dst[i]], 1);
}

__global__ void k_dinv(const int* __restrict__ cnt, float* __restrict__ dinv, int n) {
    int i = blockIdx.x * blockDim.x + threadIdx.x;
    if (i < n) dinv[i] = rsqrtf((float)(cnt[i] + 1));  // +1 self-loop
}

__global__ void k_scan1(const int* __restrict__ cnt, int* __restrict__ rowptr,
                        int* __restrict__ bsum, int n) {
    __shared__ int s[256];
    int t = threadIdx.x, g = blockIdx.x * 256 + t;
    int v = (g < n) ? cnt[g] : 0;
    s[t] = v; __syncthreads();
    for (int off = 1; off < 256; off <<= 1) {
        int a = (t >= off) ? s[t - off] : 0;
        __syncthreads();
        s[t] += a;
        __syncthreads();
    }
    if (g < n) rowptr[g] = s[t] - v;
    if (t == 255) bsum[blockIdx.x] = s[t];
}

__global__ void k_scan2(int* __restrict__ bsum, int nb) {
    __shared__ int s[256];
    int t = threadIdx.x;
    int v = (t < nb) ? bsum[t] : 0;
    s[t] = v; __syncthreads();
    for (int off = 1; off < 256; off <<= 1) {
        int a = (t >= off) ? s[t - off] : 0;
        __syncthreads();
        s[t] += a;
        __syncthreads();
    }
    if (t < nb) bsum[t] = s[t] - v;
}

__global__ void k_scan3(int* __restrict__ rowptr, const int* __restrict__ bsum,
                        int* __restrict__ cursor, int n, int e) {
    int g = blockIdx.x * blockDim.x + threadIdx.x;
    if (g < n) {
        int r = rowptr[g] + bsum[g >> 8];
        rowptr[g] = r;
        cursor[g] = r;
    }
    if (g == 0) rowptr[n] = e;
}

__global__ void k_scatter(const int* __restrict__ src, const int* __restrict__ dst,
                          int* __restrict__ cursor, int* __restrict__ col, int e) {
    int i = blockIdx.x * blockDim.x + threadIdx.x;
    if (i < e) {
        int p = atomicAdd(&cursor[dst[i]], 1);
        col[p] = src[i];
    }
}

// xb[i,:] = bf16(x[i,:] * dinv[i]); thread handles 4 floats -> 8B bf16 store.
__global__ void k_xscale(const float* __restrict__ x, const float* __restrict__ dinv,
                         unsigned int* __restrict__ xb2, int n) {
    int i = blockIdx.x * blockDim.x + threadIdx.x;  // over n*32
    if (i >= n * 32) return;
    float di = dinv[i >> 5];
    float4 v = ((const float4*)x)[i];
    unsigned int lo = (unsigned int)f2bf(v.x * di) | ((unsigned int)f2bf(v.y * di) << 16);
    unsigned int hi = (unsigned int)f2bf(v.z * di) | ((unsigned int)f2bf(v.w * di) << 16);
    xb2[i * 2] = lo;
    xb2[i * 2 + 1] = hi;
}

// Convert W (128x128 fp32 row-major, W[k][n]) into MFMA B-fragment layout:
// frag f = (n>>4)*4 + (k>>5); lane = (n&15) | (((k>>3)&3)<<4); j = k&7;
// idx = f*512 + lane*8 + j. Handles both W1 and W2 (second half of grid).
__global__ void k_wfrag(const float* __restrict__ W1, const float* __restrict__ W2,
                        unsigned short* __restrict__ w1f, unsigned short* __restrict__ w2f) {
    int i = blockIdx.x * blockDim.x + threadIdx.x;  // 0 .. 2*16384
    int which = i >> 14;
    int idx = i & 16383;
    int k = idx >> 7, n = idx & 127;
    int f = ((n >> 4) << 2) + (k >> 5);
    int lane = (n & 15) | (((k >> 3) & 3) << 4);
    int j = k & 7;
    int o = f * 512 + lane * 8 + j;
    if (which == 0) w1f[o] = f2bf(W1[idx]);
    else            w2f[o] = f2bf(W2[idx]);
}

// Pull aggregation in bf16: aggb[t] = bf16(dinv[t] * (xb[t] + sum xb[col])).
// 32 lanes/node, each lane 4 dims (8B gathers).
__global__ __launch_bounds__(256) void k_agg_pull_bf(
    const uint2* __restrict__ xb2, const int* __restrict__ rowptr,
    const int* __restrict__ col, const float* __restrict__ dinv,
    uint2* __restrict__ aggb2, int n) {
    int gid = blockIdx.x * blockDim.x + threadIdx.x;
    int node = gid >> 5;
    if (node >= n) return;
    int lane = gid & 31;
    uint2 v = xb2[(size_t)node * 32 + lane];
    float a0 = bf2f(v.x & 0xffff), a1 = bf2f(v.x >> 16);
    float a2 = bf2f(v.y & 0xffff), a3 = bf2f(v.y >> 16);
    int c0 = rowptr[node], c1 = rowptr[node + 1];
    for (int e = c0; e < c1; ++e) {
        int s = col[e];
        uint2 u = xb2[(size_t)s * 32 + lane];
        a0 += bf2f(u.x & 0xffff); a1 += bf2f(u.x >> 16);
        a2 += bf2f(u.y & 0xffff); a3 += bf2f(u.y >> 16);
    }
    float di = dinv[node];
    uint2 o;
    o.x = (unsigned int)f2bf(a0 * di) | ((unsigned int)f2bf(a1 * di) << 16);
    o.y = (unsigned int)f2bf(a2 * di) | ((unsigned int)f2bf(a3 * di) << 16);
    aggb2[(size_t)node * 32 + lane] = o;
}

// Fused GEMM1(+bias+tanh) -> LDS -> GEMM2(+bias) -> fp32 out.
// 64 rows/block, 4 waves; each wave does a 16-row strip x 128 cols.
// A-frag: A[m=lane&15][k=(lane>>4)*8+j]; B-frag from pre-swizzled w*f;
// D: col=lane&15, row=(lane>>4)*4+reg (m89-verified layouts).
__global__ __launch_bounds__(256) void k_fused_gemm(
    const unsigned short* __restrict__ aggb, const unsigned short* __restrict__ w1f,
    const float* __restrict__ b1, const unsigned short* __restrict__ w2f,
    const float* __restrict__ b2, float* __restrict__ out, int m) {
    __shared__ unsigned short hs[64 * 136];  // 136-pitch: 16B-aligned rows, 2-way-free
    const int t = threadIdx.x;
    const int wave = t >> 6, l = t & 63;
    const int kq = l >> 4;              // 0..3
    const int lc = l & 15;
    const int row_local = wave * 16 + lc;
    int row = blockIdx.x * 64 + row_local;
    int rowc = min(row, m - 1);         // clamp for tail-block loads

    float4v acc[8];
    for (int ct = 0; ct < 8; ++ct) acc[ct] = (float4v){0.f, 0.f, 0.f, 0.f};
    for (int kc = 0; kc < 4; ++kc) {
        short8 a = *(const short8*)(aggb + (size_t)rowc * DFEAT + kc * 32 + kq * 8);
        for (int ct = 0; ct < 8; ++ct) {
            short8 b = *(const short8*)(w1f + (ct * 4 + kc) * 512 + l * 8);
            acc[ct] = __builtin_amdgcn_mfma_f32_16x16x32_bf16(a, b, acc[ct], 0, 0, 0);
        }
    }
    // bias + tanh -> LDS (bf16), D-layout scatter
    const int drow0 = wave * 16 + kq * 4;
    for (int ct = 0; ct < 8; ++ct) {
        float bb = b1[ct * 16 + lc];
        for (int r = 0; r < 4; ++r) {
            float v = tanhf(acc[ct][r] + bb);
            hs[(drow0 + r) * 136 + ct * 16 + lc] = f2bf(v);
        }
    }
    __syncthreads();

    float4v acc2[8];
    for (int ct = 0; ct < 8; ++ct) acc2[ct] = (float4v){0.f, 0.f, 0.f, 0.f};
    for (int kc = 0; kc < 4; ++kc) {
        short8 a = *(const short8*)(hs + row_local * 136 + kc * 32 + kq * 8);
        for (int ct = 0; ct < 8; ++ct) {
            short8 b = *(const short8*)(w2f + (ct * 4 + kc) * 512 + l * 8);
            acc2[ct] = __builtin_amdgcn_mfma_f32_16x16x32_bf16(a, b, acc2[ct], 0, 0, 0);
        }
    }
    const int orow0 = blockIdx.x * 64 + drow0;
    for (int ct = 0; ct < 8; ++ct) {
        float bb = b2[ct * 16 + lc];
        for (int r = 0; r < 4; ++r) {
            int orow = orow0 + r;
            if (orow < m) out[(size_t)orow * DFEAT + ct * 16 + lc] = acc2[ct][r] + bb;
        }
    }
}

static inline size_t align256(size_t v) { return (v + 255) & ~(size_t)255; }

extern "C" void kernel_launch(void* const* d_in, const int* in_sizes, int n_in,
                              void* d_out, int out_size, void* d_ws, size_t ws_size,
                              hipStream_t stream) {
    const float* x  = (const float*)d_in[0];
    const int*   ei = (const int*)d_in[1];
    const float* W1 = (const float*)d_in[2];
    const float* b1 = (const float*)d_in[3];
    const float* W2 = (const float*)d_in[4];
    const float* b2 = (const float*)d_in[5];
    float* out = (float*)d_out;

    const int N = in_sizes[0] / DFEAT;   // 50000
    const int E = in_sizes[1] / 2;       // 640000
    const int* src = ei;
    const int* dst = ei + E;

    char* ws = (char*)d_ws;
    size_t off = 0;
    int* cnt    = (int*)(ws + off);   off += align256((size_t)N * 4);
    float* dinv = (float*)(ws + off); off += align256((size_t)N * 4);
    int* rowptr = (int*)(ws + off);   off += align256((size_t)(N + 1) * 4);
    int* cursor = (int*)(ws + off);   off += align256((size_t)N * 4);
    int* bsum   = (int*)(ws + off);   off += align256(256 * 4);
    int* col    = (int*)(ws + off);   off += align256((size_t)E * 4);
    unsigned short* xb   = (unsigned short*)(ws + off); off += align256((size_t)N * DFEAT * 2);
    unsigned short* aggb = (unsigned short*)(ws + off); off += align256((size_t)N * DFEAT * 2);
    unsigned short* w1f  = (unsigned short*)(ws + off); off += align256((size_t)DFEAT * DFEAT * 2);
    unsigned short* w2f  = (unsigned short*)(ws + off); off += align256((size_t)DFEAT * DFEAT * 2);

    const int nb = (N + 255) / 256;  // 196 <= 256 (k_scan2 single-block limit)

    k_cnt_init<<<nb, 256, 0, stream>>>(cnt, N);
    k_cnt_count<<<(E + 255) / 256, 256, 0, stream>>>(dst, cnt, E);
    k_dinv<<<nb, 256, 0, stream>>>(cnt, dinv, N);
    k_scan1<<<nb, 256, 0, stream>>>(cnt, rowptr, bsum, N);
    k_scan2<<<1, 256, 0, stream>>>(bsum, nb);
    k_scan3<<<nb, 256, 0, stream>>>(rowptr, bsum, cursor, N, E);
    k_scatter<<<(E + 255) / 256, 256, 0, stream>>>(src, dst, cursor, col, E);
    k_xscale<<<(N * 32 + 255) / 256, 256, 0, stream>>>(x, dinv, (unsigned int*)xb, N);
    k_wfrag<<<(2 * DFEAT * DFEAT + 255) / 256, 256, 0, stream>>>(W1, W2, w1f, w2f);
    k_agg_pull_bf<<<(N * 32 + 255) / 256, 256, 0, stream>>>(
        (const uint2*)xb, rowptr, col, dinv, (uint2*)aggb, N);
    k_fused_gemm<<<(N + 63) / 64, 256, 0, stream>>>(aggb, w1f, b1, w2f, b2, out, N);
}